// Round 1
// baseline (249.475 us; speedup 1.0000x reference)
//
#include <hip/hip_runtime.h>
#include <math.h>

// Problem constants
#define Bsz   16
#define Lseq  512
#define Nfeat 32
#define E     128
#define EMB   8
#define FCH   64
#define Hd    256
#define PRE   96
#define M     16384   // N*L
#define MH    8193    // M/2+1
#define LAMBDA 0.01f

// workspace layout (float offsets)
#define OFF_W   0          // twiddle table: 16384 x {cos,sin} = 32768 floats
#define OFF_G   32768      // four-step intermediate: 16*128*128*2 = 524288 floats
#define OFF_CS  32768      // C/S table (overlays G after fft passes): 8193*16 floats
#define OFF_X   557056     // spectrum: 16 * XSTRIDE * 2 floats
#define XSTRIDE 8200
#define OFF_H0  819456     // h0_z: 16*1024 floats
// total = 835840 floats = 3.34 MB

__device__ __forceinline__ float shrinkf(float v) {
  return v > LAMBDA ? v - LAMBDA : (v < -LAMBDA ? v + LAMBDA : 0.0f);
}

// ---------- twiddle table: W[k] = (cos, sin)(2*pi*k/M), k=0..M-1 ----------
__global__ void k_twiddle(float* __restrict__ ws) {
  int k = blockIdx.x * 256 + threadIdx.x;   // grid 64x256 == 16384 exactly
  float s, c;
  sincosf((float)k * 3.83495196971410293e-4f, &s, &c);  // 2*pi/16384
  ws[OFF_W + 2 * k]     = c;
  ws[OFF_W + 2 * k + 1] = s;
}

// ---------- forward DFT pass A+B: G'[b,f1,t1] ----------
// x_flat[b,t] with t = t1 + 128*t2 ; t = n*512+l -> x[b,l,n]
__global__ void k_fft1(const float* __restrict__ x, float* __restrict__ ws) {
  int b = blockIdx.y;
  int t1base = blockIdx.x * 2;          // grid.x = 64
  __shared__ float xcol[2][128];
  __shared__ float wc[128], wsn[128];
  int tid = threadIdx.x;
  if (tid < 128) {                       // W128[k] = W16384[128k]
    wc[tid]  = ws[OFF_W + 2 * (tid * 128)];
    wsn[tid] = ws[OFF_W + 2 * (tid * 128) + 1];
  }
  {
    int t1loc = tid >> 7, t2 = tid & 127;
    int t = (t1base + t1loc) + 128 * t2;
    int n = t >> 9, l = t & 511;
    xcol[t1loc][t2] = x[b * (Lseq * Nfeat) + l * Nfeat + n];
  }
  __syncthreads();
  int f1 = tid & 127, t1loc = tid >> 7;
  int t1 = t1base + t1loc;
  float gr = 0.f, gi = 0.f;
  int k = 0;
  #pragma unroll 8
  for (int t2 = 0; t2 < 128; ++t2) {
    float xv = xcol[t1loc][t2];
    gr += xv * wc[k];
    gi -= xv * wsn[k];
    k = (k + f1) & 127;
  }
  // twiddle by W16384^{f1*t1} (e^{-i theta})
  int kk = (f1 * t1) & (M - 1);
  float cb = ws[OFF_W + 2 * kk], sb = ws[OFF_W + 2 * kk + 1];
  float grr = gr * cb + gi * sb;
  float gii = gi * cb - gr * sb;
  float* G = ws + OFF_G + (((b * 128 + f1) * 128) + t1) * 2;
  G[0] = grr;
  G[1] = gii;
}

// ---------- forward DFT pass C: X[b, f1+128*f2] = sum_t1 G'[b,f1,t1] W128^{f2 t1} ----------
__global__ void k_fft2(float* __restrict__ ws) {
  int b = blockIdx.y;
  int f1base = blockIdx.x * 2;          // grid.x = 64
  __shared__ float Gs[2][256];
  __shared__ float wc[128], wsn[128];
  int tid = threadIdx.x;
  if (tid < 128) {
    wc[tid]  = ws[OFF_W + 2 * (tid * 128)];
    wsn[tid] = ws[OFF_W + 2 * (tid * 128) + 1];
  }
  for (int j = tid; j < 512; j += 256) {
    int f1loc = j >> 8, r = j & 255;
    Gs[f1loc][r] = ws[OFF_G + ((b * 128 + f1base + f1loc) * 256) + r];
  }
  __syncthreads();
  int f2 = tid & 127, f1loc = tid >> 7;
  float xr = 0.f, xi = 0.f;
  int k = 0;
  #pragma unroll 8
  for (int t1 = 0; t1 < 128; ++t1) {
    float gr = Gs[f1loc][2 * t1], gi = Gs[f1loc][2 * t1 + 1];
    float c = wc[k], s = wsn[k];
    xr += gr * c + gi * s;
    xi += gi * c - gr * s;
    k = (k + f2) & 127;
  }
  int f = (f1base + f1loc) + 128 * f2;
  if (f <= 8192) {
    float* X = ws + OFF_X + (b * XSTRIDE + f) * 2;
    X[0] = xr;
    X[1] = xi;
  }
}

// ---------- C/S tables: C[f,m], S[f,m] (overlays G region; run after fft2) ----------
__global__ void k_cs(const float* __restrict__ emb10, float* __restrict__ ws) {
  __shared__ float e10[Lseq * EMB];
  for (int i = threadIdx.x; i < Lseq * EMB; i += 256) e10[i] = emb10[i];
  __syncthreads();
  int f = blockIdx.x * 256 + threadIdx.x;   // grid 33x256
  if (f > 8192) return;
  const float* wt = ws + OFF_W;
  float ca[EMB], sa[EMB];
  #pragma unroll
  for (int m = 0; m < EMB; ++m) { ca[m] = 0.f; sa[m] = 0.f; }
  int k = 0;
  for (int t = 0; t < Lseq; ++t) {
    float c = wt[2 * k], s = wt[2 * k + 1];
    #pragma unroll
    for (int m = 0; m < EMB; ++m) {
      ca[m] += c * e10[t * EMB + m];
      sa[m] += s * e10[t * EMB + m];
    }
    k = (k + f) & (M - 1);
  }
  float wf = (f == 0 || f == 8192) ? (1.0f / 128.0f) : (2.0f / 128.0f);
  float* o = ws + OFF_CS + f * 16;
  #pragma unroll
  for (int m = 0; m < EMB; ++m) { o[m] = ca[m] * wf; o[8 + m] = sa[m] * wf; }
}

// ---------- fused fourierGC + partial-irfft reduction over f ----------
#define FCHUNK 256
__global__ void k_gc(const float* __restrict__ emb,
                     const float* __restrict__ w0, const float* __restrict__ b0,
                     const float* __restrict__ w1, const float* __restrict__ b1,
                     const float* __restrict__ w2, const float* __restrict__ b2,
                     float* __restrict__ ws) {
  int b = blockIdx.y;                         // grid (33, 16)
  int fstart = blockIdx.x * FCHUNK;
  int fcount = min(FCHUNK, MH - fstart);
  __shared__ float Xs[FCHUNK * 2];
  __shared__ float CSs[FCHUNK * 16];
  int tid = threadIdx.x;
  for (int j = tid; j < fcount * 2; j += 256)
    Xs[j] = ws[OFF_X + (b * XSTRIDE + fstart) * 2 + j];
  for (int j = tid; j < fcount * 16; j += 256)
    CSs[j] = ws[OFF_CS + fstart * 16 + j];
  __syncthreads();
  int e = tid & 127, fh = tid >> 7;
  float se  = emb[e] * (1.0f / 128.0f);       // ortho forward scale folded in
  float d00 = w0[e * 129], d01 = w0[E * E + e * 129];
  float c00 = b0[e],       c01 = b0[E + e];
  float d10 = w1[e * 129], d11 = w1[E * E + e * 129];
  float c10 = b1[e],       c11 = b1[E + e];
  float d20 = w2[e * 129], d21 = w2[E * E + e * 129];
  float c20 = b2[e],       c21 = b2[E + e];
  float acc[EMB];
  #pragma unroll
  for (int m = 0; m < EMB; ++m) acc[m] = 0.f;

  for (int i = fh; i < fcount; i += 2) {
    float xr = Xs[2 * i] * se, xi = Xs[2 * i + 1] * se;
    float or0 = fmaxf(xr * d00 - xi * d01 + c00, 0.f);
    float oi0 = fmaxf(xi * d00 + xr * d01 + c01, 0.f);
    float pr = shrinkf(or0), pi = shrinkf(oi0);
    float or1 = fmaxf(or0 * d10 - oi0 * d11 + c10, 0.f);
    float oi1 = fmaxf(oi0 * d10 + or1 * d11 + c11, 0.f);
    pr += shrinkf(or1); pi += shrinkf(oi1);
    float or2 = fmaxf(or1 * d20 - oi1 * d21 + c20, 0.f);
    float oi2 = fmaxf(oi1 * d20 + or2 * d21 + c21, 0.f);
    float zr = shrinkf(or2) + pr;
    float zi = shrinkf(oi2) + pi;
    const float* cs = &CSs[i * 16];
    #pragma unroll
    for (int m = 0; m < EMB; ++m) acc[m] += zr * cs[m] - zi * cs[8 + m];
  }
  float* h0 = ws + OFF_H0 + b * (E * EMB) + e * EMB;
  #pragma unroll
  for (int m = 0; m < EMB; ++m) atomicAdd(&h0[m], acc[m]);
}

// ---------- bias skip + FC head (n=0 only) ----------
__global__ void k_fc(const float* __restrict__ x, const float* __restrict__ emb,
                     const float* __restrict__ emb10,
                     const float* __restrict__ fc1w, const float* __restrict__ fc1b,
                     const float* __restrict__ fc2w, const float* __restrict__ fc2b,
                     const float* __restrict__ fc3w, const float* __restrict__ fc3b,
                     const float* __restrict__ ws, float* __restrict__ out) {
  int b = blockIdx.x;                         // grid 16
  __shared__ float h0s[E * EMB];
  __shared__ float h1s[FCH];
  __shared__ float h2s[Hd];
  __shared__ float hxs[EMB];
  __shared__ float part[256];
  int tid = threadIdx.x;
  {
    int m = tid & 7, g = tid >> 3;            // 32 groups x 8 m
    float p = 0.f;
    for (int l = g; l < Lseq; l += 32)
      p += x[b * (Lseq * Nfeat) + l * Nfeat + 0] * emb10[l * EMB + m];
    part[tid] = p;                            // part[g*8+m] == part[tid]
  }
  __syncthreads();
  if (tid < 8) {
    float s = 0.f;
    for (int g = 0; g < 32; ++g) s += part[g * 8 + tid];
    hxs[tid] = s;
  }
  __syncthreads();
  for (int k = tid; k < E * EMB; k += 256)
    h0s[k] = ws[OFF_H0 + b * (E * EMB) + k] + emb[k >> 3] * hxs[k & 7];
  __syncthreads();
  if (tid < FCH) {
    float a = fc1b[tid];
    for (int k = 0; k < E * EMB; ++k) a += h0s[k] * fc1w[tid * (E * EMB) + k];
    h1s[tid] = a > 0.f ? a : 0.01f * a;
  }
  __syncthreads();
  {
    float a = fc2b[tid];
    for (int c = 0; c < FCH; ++c) a += h1s[c] * fc2w[tid * FCH + c];
    h2s[tid] = a > 0.f ? a : 0.01f * a;
  }
  __syncthreads();
  if (tid < PRE) {
    float a = fc3b[tid];
    for (int j = 0; j < Hd; ++j) a += h2s[j] * fc3w[tid * Hd + j];
    out[b * PRE + tid] = a;
  }
}

extern "C" void kernel_launch(void* const* d_in, const int* in_sizes, int n_in,
                              void* d_out, int out_size, void* d_ws, size_t ws_size,
                              hipStream_t stream) {
  const float* x     = (const float*)d_in[0];
  const float* emb   = (const float*)d_in[1];
  const float* w0    = (const float*)d_in[2];
  const float* b0    = (const float*)d_in[3];
  const float* w1    = (const float*)d_in[4];
  const float* b1    = (const float*)d_in[5];
  const float* w2    = (const float*)d_in[6];
  const float* b2    = (const float*)d_in[7];
  const float* emb10 = (const float*)d_in[8];
  const float* fc1w  = (const float*)d_in[9];
  const float* fc1b  = (const float*)d_in[10];
  const float* fc2w  = (const float*)d_in[11];
  const float* fc2b  = (const float*)d_in[12];
  const float* fc3w  = (const float*)d_in[13];
  const float* fc3b  = (const float*)d_in[14];
  float* ws  = (float*)d_ws;
  float* out = (float*)d_out;

  hipMemsetAsync(ws + OFF_H0, 0, Bsz * E * EMB * sizeof(float), stream);
  k_twiddle<<<dim3(64), 256, 0, stream>>>(ws);
  k_fft1<<<dim3(64, Bsz), 256, 0, stream>>>(x, ws);
  k_fft2<<<dim3(64, Bsz), 256, 0, stream>>>(ws);
  k_cs<<<dim3(33), 256, 0, stream>>>(emb10, ws);   // overlays G region (dead now)
  k_gc<<<dim3(33, Bsz), 256, 0, stream>>>(emb, w0, b0, w1, b1, w2, b2, ws);
  k_fc<<<dim3(Bsz), 256, 0, stream>>>(x, emb, emb10, fc1w, fc1b, fc2w, fc2b,
                                      fc3w, fc3b, ws, out);
}

// Round 2
// 181.590 us; speedup vs baseline: 1.3738x; 1.3738x over previous
//
#include <hip/hip_runtime.h>
#include <math.h>

// Problem constants
#define Bsz   16
#define Lseq  512
#define Nfeat 32
#define E     128
#define EMB   8
#define FCH   64
#define Hd    256
#define PRE   96
#define M     16384   // N*L
#define MH    8193    // M/2+1
#define LAMBDA 0.01f

// workspace layout (float offsets)
#define OFF_W   0          // twiddle table: 16384 x {cos,sin} = 32768 floats
#define OFF_G   32768      // four-step intermediate: 16*128*128*2 = 524288 floats
#define OFF_CS  32768      // C/S table (overlays G after fft passes): 8193*16 floats
#define OFF_X   557056     // spectrum: 16 * XSTRIDE * 2 floats
#define XSTRIDE 8200
#define OFF_P   819456     // partials: 65*16*1024 = 1064960 floats
// total = 1884416 floats = 7.54 MB

__global__ void k_twiddle(float* __restrict__ ws) {
  int k = blockIdx.x * 256 + threadIdx.x;   // grid 64x256 == 16384
  float s, c;
  sincosf((float)k * 3.83495196971410293e-4f, &s, &c);  // 2*pi/16384
  ws[OFF_W + 2 * k]     = c;
  ws[OFF_W + 2 * k + 1] = s;
}

// ---------- forward DFT pass A+B: G'[b,f1,t1] ----------
__global__ void k_fft1(const float* __restrict__ x, float* __restrict__ ws) {
  int b = blockIdx.y;
  int t1base = blockIdx.x * 2;          // grid.x = 64
  __shared__ float xcol[2][128];
  int tid = threadIdx.x;
  int t1loc = tid >> 7, idx = tid & 127;
  {
    int t = (t1base + t1loc) + 128 * idx;
    int n = t >> 9, l = t & 511;
    xcol[t1loc][idx] = x[b * (Lseq * Nfeat) + l * Nfeat + n];
  }
  __syncthreads();
  int f1 = idx, t1 = t1base + t1loc;
  // rotation step e^{-i 2pi f1/128}; two interleaved chains (step^2) for ILP
  float c1 = ws[OFF_W + 2 * (f1 << 7)];
  float s1 = ws[OFF_W + 2 * (f1 << 7) + 1];
  float c2 = c1 * c1 - s1 * s1;
  float s2 = 2.0f * s1 * c1;
  float cA = 1.f, sA = 0.f, cB = c1, sB = s1;
  float grA = 0.f, giA = 0.f, grB = 0.f, giB = 0.f;
  #pragma unroll 8
  for (int t2 = 0; t2 < 128; t2 += 2) {
    float xv0 = xcol[t1loc][t2];
    float xv1 = xcol[t1loc][t2 + 1];
    grA = fmaf(xv0, cA, grA);  giA = fmaf(xv0, -sA, giA);
    grB = fmaf(xv1, cB, grB);  giB = fmaf(xv1, -sB, giB);
    float cn = cA * c2 - sA * s2; sA = sA * c2 + cA * s2; cA = cn;
    cn = cB * c2 - sB * s2;       sB = sB * c2 + cB * s2; cB = cn;
  }
  float gr = grA + grB, gi = giA + giB;
  int kk = f1 * t1;                      // <= 127*127 < 16384
  float cb = ws[OFF_W + 2 * kk], sb = ws[OFF_W + 2 * kk + 1];
  float grr = gr * cb + gi * sb;
  float gii = gi * cb - gr * sb;
  float* G = ws + OFF_G + (((b * 128 + f1) * 128) + t1) * 2;
  G[0] = grr;
  G[1] = gii;
}

// ---------- forward DFT pass C ----------
__global__ void k_fft2(float* __restrict__ ws) {
  int b = blockIdx.y;
  int f1base = blockIdx.x * 2;          // grid.x = 64
  __shared__ __align__(16) float2 Gs[2][128];
  int tid = threadIdx.x;
  {
    int f1loc = tid >> 7, r = tid & 127;
    Gs[f1loc][r] = ((const float2*)(ws + OFF_G))[(b * 128 + f1base + f1loc) * 128 + r];
  }
  __syncthreads();
  int f2 = tid & 127, f1loc = tid >> 7;
  int f = (f1base + f1loc) + 128 * f2;
  if (f > 8192) return;                  // whole waves exit for wasted halves
  float c1 = ws[OFF_W + 2 * (f2 << 7)];
  float s1 = ws[OFF_W + 2 * (f2 << 7) + 1];
  float c2 = c1 * c1 - s1 * s1;
  float s2 = 2.0f * s1 * c1;
  float cA = 1.f, sA = 0.f, cB = c1, sB = s1;
  float xrA = 0.f, xiA = 0.f, xrB = 0.f, xiB = 0.f;
  #pragma unroll 8
  for (int t1 = 0; t1 < 128; t1 += 2) {
    float2 g0 = Gs[f1loc][t1];
    float2 g1 = Gs[f1loc][t1 + 1];
    xrA = fmaf(g0.x, cA, xrA); xrA = fmaf(g0.y, sA, xrA);
    xiA = fmaf(g0.y, cA, xiA); xiA = fmaf(-g0.x, sA, xiA);
    xrB = fmaf(g1.x, cB, xrB); xrB = fmaf(g1.y, sB, xrB);
    xiB = fmaf(g1.y, cB, xiB); xiB = fmaf(-g1.x, sB, xiB);
    float cn = cA * c2 - sA * s2; sA = sA * c2 + cA * s2; cA = cn;
    cn = cB * c2 - sB * s2;       sB = sB * c2 + cB * s2; cB = cn;
  }
  float* X = ws + OFF_X + (b * XSTRIDE + f) * 2;
  X[0] = xrA + xrB;
  X[1] = xiA + xiB;
}

// ---------- C/S tables ----------
__global__ void k_cs(const float* __restrict__ emb10, float* __restrict__ ws) {
  __shared__ float e10[Lseq * EMB];
  int tid = threadIdx.x;
  for (int i = tid; i < Lseq * EMB; i += 256) e10[i] = emb10[i];
  __syncthreads();
  int floc = tid >> 5, tl = tid & 31;
  int f = blockIdx.x * 8 + floc;        // grid 1025
  if (f > 8192) return;
  const float* wt = ws + OFF_W;
  float ca[EMB], sa[EMB];
  #pragma unroll
  for (int m = 0; m < EMB; ++m) { ca[m] = 0.f; sa[m] = 0.f; }
  #pragma unroll 4
  for (int i = 0; i < 16; ++i) {
    int t = tl + 32 * i;
    int k = (f * t) & (M - 1);
    float cc = wt[2 * k], ss = wt[2 * k + 1];
    const float* er = e10 + t * EMB;
    #pragma unroll
    for (int m = 0; m < EMB; ++m) {
      ca[m] = fmaf(cc, er[m], ca[m]);
      sa[m] = fmaf(ss, er[m], sa[m]);
    }
  }
  #pragma unroll
  for (int off = 16; off >= 1; off >>= 1) {
    #pragma unroll
    for (int m = 0; m < EMB; ++m) {
      ca[m] += __shfl_xor(ca[m], off, 64);
      sa[m] += __shfl_xor(sa[m], off, 64);
    }
  }
  if (tl == 0) {
    float wf = (f == 0 || f == 8192) ? (1.0f / 128.0f) : (2.0f / 128.0f);
    float* o = ws + OFF_CS + f * 16;
    #pragma unroll
    for (int m = 0; m < EMB; ++m) { o[m] = ca[m] * wf; o[8 + m] = sa[m] * wf; }
  }
}

// ---------- fused fourierGC + partial-irfft reduction ----------
#define FCHUNK 128
__global__ void k_gc(const float* __restrict__ emb,
                     const float* __restrict__ w0, const float* __restrict__ b0,
                     const float* __restrict__ w1, const float* __restrict__ b1,
                     const float* __restrict__ w2, const float* __restrict__ b2,
                     float* __restrict__ ws) {
  int b = blockIdx.y;                         // grid (65, 16)
  int fstart = blockIdx.x * FCHUNK;
  int fcount = min(FCHUNK, MH - fstart);
  __shared__ __align__(16) float Xs[FCHUNK * 2];
  __shared__ __align__(16) float CSs[FCHUNK * 16];
  __shared__ float red[E * EMB];
  int tid = threadIdx.x;
  {
    const float4* src = (const float4*)(ws + OFF_X + (b * XSTRIDE + fstart) * 2);
    float4* dst = (float4*)Xs;
    for (int j = tid; j < (fcount * 2 + 3) / 4; j += 256) dst[j] = src[j];
    const float4* src2 = (const float4*)(ws + OFF_CS + fstart * 16);
    float4* dst2 = (float4*)CSs;
    for (int j = tid; j < fcount * 4; j += 256) dst2[j] = src2[j];
  }
  __syncthreads();
  int e = tid & 127, fh = tid >> 7;
  float se  = emb[e] * (1.0f / 128.0f);
  float d00 = w0[e * 129], d01 = w0[E * E + e * 129];
  float c00 = b0[e],       c01 = b0[E + e];
  float d10 = w1[e * 129], d11 = w1[E * E + e * 129];
  float c10 = b1[e],       c11 = b1[E + e];
  float d20 = w2[e * 129], d21 = w2[E * E + e * 129];
  float c20 = b2[e],       c21 = b2[E + e];
  float acc[EMB];
  #pragma unroll
  for (int m = 0; m < EMB; ++m) acc[m] = 0.f;

  for (int i = fh; i < fcount; i += 2) {
    float xr = Xs[2 * i] * se, xi = Xs[2 * i + 1] * se;
    float or0 = fmaxf(fmaf(xr, d00, fmaf(-xi, d01, c00)), 0.f);
    float oi0 = fmaxf(fmaf(xi, d00, fmaf(xr, d01, c01)), 0.f);
    float pr = fmaxf(or0 - LAMBDA, 0.f), pi = fmaxf(oi0 - LAMBDA, 0.f);
    float or1 = fmaxf(fmaf(or0, d10, fmaf(-oi0, d11, c10)), 0.f);
    float oi1 = fmaxf(fmaf(oi0, d10, fmaf(or1, d11, c11)), 0.f);
    pr += fmaxf(or1 - LAMBDA, 0.f); pi += fmaxf(oi1 - LAMBDA, 0.f);
    float or2 = fmaxf(fmaf(or1, d20, fmaf(-oi1, d21, c20)), 0.f);
    float oi2 = fmaxf(fmaf(oi1, d20, fmaf(or2, d21, c21)), 0.f);
    float zr = fmaxf(or2 - LAMBDA, 0.f) + pr;
    float zi = fmaxf(oi2 - LAMBDA, 0.f) + pi;
    const float4* cs4 = (const float4*)&CSs[i * 16];
    float4 cA = cs4[0], cB = cs4[1], sA = cs4[2], sB = cs4[3];
    acc[0] = fmaf(zr, cA.x, fmaf(-zi, sA.x, acc[0]));
    acc[1] = fmaf(zr, cA.y, fmaf(-zi, sA.y, acc[1]));
    acc[2] = fmaf(zr, cA.z, fmaf(-zi, sA.z, acc[2]));
    acc[3] = fmaf(zr, cA.w, fmaf(-zi, sA.w, acc[3]));
    acc[4] = fmaf(zr, cB.x, fmaf(-zi, sB.x, acc[4]));
    acc[5] = fmaf(zr, cB.y, fmaf(-zi, sB.y, acc[5]));
    acc[6] = fmaf(zr, cB.z, fmaf(-zi, sB.z, acc[6]));
    acc[7] = fmaf(zr, cB.w, fmaf(-zi, sB.w, acc[7]));
  }
  if (fh == 1) {
    #pragma unroll
    for (int m = 0; m < EMB; ++m) red[e * EMB + m] = acc[m];
  }
  __syncthreads();
  if (fh == 0) {
    float* P = ws + OFF_P + (blockIdx.x * 16 + b) * (E * EMB) + e * EMB;
    #pragma unroll
    for (int m = 0; m < EMB; ++m) P[m] = acc[m] + red[e * EMB + m];
  }
}

// ---------- partial reduce + bias skip + FC head ----------
__global__ void k_fc(const float* __restrict__ x, const float* __restrict__ emb,
                     const float* __restrict__ emb10,
                     const float* __restrict__ fc1w, const float* __restrict__ fc1b,
                     const float* __restrict__ fc2w, const float* __restrict__ fc2b,
                     const float* __restrict__ fc3w, const float* __restrict__ fc3b,
                     const float* __restrict__ ws, float* __restrict__ out) {
  int b = blockIdx.x;                         // grid 16
  __shared__ float h0s[E * EMB];
  __shared__ float h1s[FCH];
  __shared__ float h2s[Hd];
  __shared__ float hxs[EMB];
  __shared__ float scratch[256];
  int tid = threadIdx.x;
  {
    int m = tid & 7, g = tid >> 3;            // 32 groups x 8 m
    float p = 0.f;
    for (int l = g; l < Lseq; l += 32)
      p = fmaf(x[b * (Lseq * Nfeat) + l * Nfeat], emb10[l * EMB + m], p);
    scratch[tid] = p;
  }
  __syncthreads();
  if (tid < 8) {
    float s = 0.f;
    for (int g = 0; g < 32; ++g) s += scratch[g * 8 + tid];
    hxs[tid] = s;
  }
  __syncthreads();
  for (int k = tid; k < E * EMB; k += 256) {
    float a = emb[k >> 3] * hxs[k & 7];
    const float* P = ws + OFF_P + b * (E * EMB) + k;
    #pragma unroll 13
    for (int c = 0; c < 65; ++c) a += P[c * (16 * E * EMB)];
    h0s[k] = a;
  }
  __syncthreads();
  {
    int o = tid & 63, kc = tid >> 6;          // 4-way K split
    const float* wrow = fc1w + o * (E * EMB) + kc * 256;
    const float* hh = h0s + kc * 256;
    float a = 0.f;
    #pragma unroll 8
    for (int k = 0; k < 256; ++k) a = fmaf(hh[k], wrow[k], a);
    scratch[tid] = a;
  }
  __syncthreads();
  if (tid < FCH) {
    float a = fc1b[tid] + scratch[tid] + scratch[tid + 64] +
              scratch[tid + 128] + scratch[tid + 192];
    h1s[tid] = a > 0.f ? a : 0.01f * a;
  }
  __syncthreads();
  {
    float a = fc2b[tid];
    const float* wrow = fc2w + tid * FCH;
    #pragma unroll 8
    for (int c = 0; c < FCH; ++c) a = fmaf(h1s[c], wrow[c], a);
    h2s[tid] = a > 0.f ? a : 0.01f * a;
  }
  __syncthreads();
  {
    int o = tid & 127, kc = tid >> 7;         // 2-way K split
    float a = 0.f;
    if (o < PRE) {
      const float* wrow = fc3w + o * Hd + kc * 128;
      const float* hh = h2s + kc * 128;
      #pragma unroll 8
      for (int k = 0; k < 128; ++k) a = fmaf(hh[k], wrow[k], a);
    }
    scratch[tid] = a;
  }
  __syncthreads();
  if (tid < PRE) out[b * PRE + tid] = fc3b[tid] + scratch[tid] + scratch[tid + 128];
}

extern "C" void kernel_launch(void* const* d_in, const int* in_sizes, int n_in,
                              void* d_out, int out_size, void* d_ws, size_t ws_size,
                              hipStream_t stream) {
  const float* x     = (const float*)d_in[0];
  const float* emb   = (const float*)d_in[1];
  const float* w0    = (const float*)d_in[2];
  const float* b0    = (const float*)d_in[3];
  const float* w1    = (const float*)d_in[4];
  const float* b1    = (const float*)d_in[5];
  const float* w2    = (const float*)d_in[6];
  const float* b2    = (const float*)d_in[7];
  const float* emb10 = (const float*)d_in[8];
  const float* fc1w  = (const float*)d_in[9];
  const float* fc1b  = (const float*)d_in[10];
  const float* fc2w  = (const float*)d_in[11];
  const float* fc2b  = (const float*)d_in[12];
  const float* fc3w  = (const float*)d_in[13];
  const float* fc3b  = (const float*)d_in[14];
  float* ws  = (float*)d_ws;
  float* out = (float*)d_out;

  k_twiddle<<<dim3(64), 256, 0, stream>>>(ws);
  k_fft1<<<dim3(64, Bsz), 256, 0, stream>>>(x, ws);
  k_fft2<<<dim3(64, Bsz), 256, 0, stream>>>(ws);
  k_cs<<<dim3(1025), 256, 0, stream>>>(emb10, ws);
  k_gc<<<dim3(65, Bsz), 256, 0, stream>>>(emb, w0, b0, w1, b1, w2, b2, ws);
  k_fc<<<dim3(Bsz), 256, 0, stream>>>(x, emb, emb10, fc1w, fc1b, fc2w, fc2b,
                                      fc3w, fc3b, ws, out);
}

// Round 3
// 176.601 us; speedup vs baseline: 1.4126x; 1.0282x over previous
//
#include <hip/hip_runtime.h>
#include <math.h>

// Problem constants
#define Bsz   16
#define Lseq  512
#define Nfeat 32
#define E     128
#define EMB   8
#define FCH   64
#define Hd    256
#define PRE   96
#define M     16384   // N*L
#define MH    8193    // M/2+1
#define LAMBDA 0.01f

// workspace layout (float offsets)
#define OFF_G   0          // four-step intermediate: 16*128*128*2 = 524288 floats
#define OFF_CS  524288     // C/S table: 8193*16 floats (rounded region)
#define OFF_P   655376     // partials: P[f1][b][k] = 128*16*1024 floats
// total ~ 2752528 floats = 11 MB

#define TWO_PI_M   3.83495196971410293e-4f   // 2*pi/16384
#define TWO_PI_128 4.90873852123405245e-2f   // 2*pi/128

// ---------- kernel 1: CS tables (blocks 0..1024) + FFT pass1 (1025..2048) ----------
__global__ __launch_bounds__(256)
void k_prep(const float* __restrict__ x, const float* __restrict__ emb10,
            float* __restrict__ ws) {
  __shared__ float smem[Lseq * EMB];   // 16 KiB (cs); fft1 uses first 256 floats
  int bid = blockIdx.x, tid = threadIdx.x;
  if (bid < 1025) {
    // ----- C/S table: C[f,m] = wf * sum_t cos(2pi f t/M) emb10[t,m], S likewise
    for (int i = tid; i < Lseq * EMB; i += 256) smem[i] = emb10[i];
    __syncthreads();
    int floc = tid >> 5, tl = tid & 31;
    int f = bid * 8 + floc;
    if (f > 8192) return;
    float ca[EMB], sa[EMB];
    #pragma unroll
    for (int m = 0; m < EMB; ++m) { ca[m] = 0.f; sa[m] = 0.f; }
    #pragma unroll 4
    for (int i = 0; i < 16; ++i) {
      int t = tl + 32 * i;
      int k = (f * t) & (M - 1);
      float ss, cc;
      sincosf((float)k * TWO_PI_M, &ss, &cc);
      const float* er = smem + t * EMB;
      #pragma unroll
      for (int m = 0; m < EMB; ++m) {
        ca[m] = fmaf(cc, er[m], ca[m]);
        sa[m] = fmaf(ss, er[m], sa[m]);
      }
    }
    #pragma unroll
    for (int off = 16; off >= 1; off >>= 1) {
      #pragma unroll
      for (int m = 0; m < EMB; ++m) {
        ca[m] += __shfl_xor(ca[m], off, 64);
        sa[m] += __shfl_xor(sa[m], off, 64);
      }
    }
    if (tl == 0) {
      float wf = (f == 0 || f == 8192) ? (1.0f / 128.0f) : (2.0f / 128.0f);
      float* o = ws + OFF_CS + f * 16;
      #pragma unroll
      for (int m = 0; m < EMB; ++m) { o[m] = ca[m] * wf; o[8 + m] = sa[m] * wf; }
    }
  } else {
    // ----- FFT pass 1: G'[b,f1,t1] = twiddle * sum_t2 x[t1+128 t2] W128^{f1 t2}
    int v = bid - 1025;                  // 0..1023
    int b = v >> 6, t1base = (v & 63) << 1;
    int t1loc = tid >> 7, idx = tid & 127;
    {
      int t = (t1base + t1loc) + 128 * idx;
      int n = t >> 9, l = t & 511;
      smem[t1loc * 128 + idx] = x[b * (Lseq * Nfeat) + l * Nfeat + n];
    }
    __syncthreads();
    int f1 = idx, t1 = t1base + t1loc;
    float s1, c1; sincosf((float)f1 * TWO_PI_128, &s1, &c1);
    float c2 = c1 * c1 - s1 * s1, s2 = 2.f * s1 * c1;
    float cA = 1.f, sA = 0.f, cB = c1, sB = s1;
    float grA = 0.f, giA = 0.f, grB = 0.f, giB = 0.f;
    const float* xc = smem + t1loc * 128;
    #pragma unroll 8
    for (int t2 = 0; t2 < 128; t2 += 2) {
      float x0 = xc[t2], x1 = xc[t2 + 1];
      grA = fmaf(x0, cA, grA); giA = fmaf(x0, -sA, giA);
      grB = fmaf(x1, cB, grB); giB = fmaf(x1, -sB, giB);
      float cn = cA * c2 - sA * s2; sA = sA * c2 + cA * s2; cA = cn;
      cn = cB * c2 - sB * s2;       sB = sB * c2 + cB * s2; cB = cn;
    }
    float gr = grA + grB, gi = giA + giB;
    float sb, cb; sincosf((float)(f1 * t1) * TWO_PI_M, &sb, &cb);
    float grr = gr * cb + gi * sb;
    float gii = gi * cb - gr * sb;
    float* G = ws + OFF_G + ((b * 128 + f1) * 128 + t1) * 2;
    G[0] = grr;
    G[1] = gii;
  }
}

// ---------- kernel 2: fused FFT pass2 + fourierGC + partial reduction ----------
__global__ __launch_bounds__(256)
void k_gcf(const float* __restrict__ emb,
           const float* __restrict__ w0, const float* __restrict__ b0,
           const float* __restrict__ w1, const float* __restrict__ b1,
           const float* __restrict__ w2, const float* __restrict__ b2,
           float* __restrict__ ws) {
  int f1 = blockIdx.x, b = blockIdx.y, tid = threadIdx.x;
  int nf2 = (f1 == 0) ? 65 : 64;       // f = f1 + 128*f2 <= 8192
  __shared__ float2 Gs[128];
  __shared__ float Xp[4][65][2];
  __shared__ float CSs[65 * 16];       // reused as red[1024] after phase B
  {
    const float2* gsrc = (const float2*)(ws + OFF_G + (b * 128 + f1) * 256);
    if (tid < 128) Gs[tid] = gsrc[tid];
    for (int j = tid; j < nf2 * 16; j += 256) {
      int i = j >> 4, m = j & 15;
      CSs[j] = ws[OFF_CS + (f1 + 128 * i) * 16 + m];
    }
  }
  __syncthreads();
  // phase A: X[f1+128 f2] = sum_t1 G'[t1] W128^{f2 t1}; t1 split into 4 quarters
  {
    int f2 = tid & 63, q = tid >> 6;
    int r = (f2 * q) & 3;              // start angle = f2*q*(pi/2): exact
    float c = (r == 0) ? 1.f : (r == 2) ? -1.f : 0.f;
    float s = (r == 1) ? 1.f : (r == 3) ? -1.f : 0.f;
    float s1, c1; sincosf((float)f2 * TWO_PI_128, &s1, &c1);
    float xr = 0.f, xi = 0.f;
    int t1 = q * 32;
    #pragma unroll 8
    for (int k = 0; k < 32; ++k) {
      float2 g = Gs[t1 + k];
      xr = fmaf(g.x, c, xr); xr = fmaf(g.y, s, xr);
      xi = fmaf(g.y, c, xi); xi = fmaf(-g.x, s, xi);
      float cn = c * c1 - s * s1; s = s * c1 + c * s1; c = cn;
    }
    Xp[q][f2][0] = xr; Xp[q][f2][1] = xi;
    if (f1 == 0 && f2 == 0) {          // extra f2=64 (f=8192): W = (-1)^t1
      float er = 0.f, ei = 0.f;
      #pragma unroll 8
      for (int k = 0; k < 32; ++k) {
        float2 g = Gs[t1 + k];
        float sg = ((t1 + k) & 1) ? -1.f : 1.f;
        er = fmaf(g.x, sg, er); ei = fmaf(g.y, sg, ei);
      }
      Xp[q][64][0] = er; Xp[q][64][1] = ei;
    }
  }
  __syncthreads();
  // phase B: GC chain + CS-weighted reduction over this block's f-set
  int e = tid & 127, fh = tid >> 7;
  float se  = emb[e] * (1.0f / 128.0f);  // ortho forward scale
  float d00 = w0[e * 129], d01 = w0[E * E + e * 129];
  float c00 = b0[e],       c01 = b0[E + e];
  float d10 = w1[e * 129], d11 = w1[E * E + e * 129];
  float c10 = b1[e],       c11 = b1[E + e];
  float d20 = w2[e * 129], d21 = w2[E * E + e * 129];
  float c20 = b2[e],       c21 = b2[E + e];
  float acc[EMB];
  #pragma unroll
  for (int m = 0; m < EMB; ++m) acc[m] = 0.f;

  for (int i = fh; i < nf2; i += 2) {
    float xr = ((Xp[0][i][0] + Xp[1][i][0]) + (Xp[2][i][0] + Xp[3][i][0])) * se;
    float xi = ((Xp[0][i][1] + Xp[1][i][1]) + (Xp[2][i][1] + Xp[3][i][1])) * se;
    float or0 = fmaxf(fmaf(xr, d00, fmaf(-xi, d01, c00)), 0.f);
    float oi0 = fmaxf(fmaf(xi, d00, fmaf(xr, d01, c01)), 0.f);
    float pr = fmaxf(or0 - LAMBDA, 0.f), pi = fmaxf(oi0 - LAMBDA, 0.f);
    float or1 = fmaxf(fmaf(or0, d10, fmaf(-oi0, d11, c10)), 0.f);
    float oi1 = fmaxf(fmaf(oi0, d10, fmaf(or1, d11, c11)), 0.f);
    pr += fmaxf(or1 - LAMBDA, 0.f); pi += fmaxf(oi1 - LAMBDA, 0.f);
    float or2 = fmaxf(fmaf(or1, d20, fmaf(-oi1, d21, c20)), 0.f);
    float oi2 = fmaxf(fmaf(oi1, d20, fmaf(or2, d21, c21)), 0.f);
    float zr = fmaxf(or2 - LAMBDA, 0.f) + pr;
    float zi = fmaxf(oi2 - LAMBDA, 0.f) + pi;
    const float* cs = &CSs[i * 16];
    #pragma unroll
    for (int m = 0; m < EMB; ++m)
      acc[m] = fmaf(zr, cs[m], fmaf(-zi, cs[8 + m], acc[m]));
  }
  __syncthreads();                      // everyone done reading CSs
  float* red = CSs;
  if (fh == 1) {
    #pragma unroll
    for (int m = 0; m < EMB; ++m) red[e * EMB + m] = acc[m];
  }
  __syncthreads();
  if (fh == 0) {
    float* P = ws + OFF_P + (f1 * 16 + b) * (E * EMB) + e * EMB;
    #pragma unroll
    for (int m = 0; m < EMB; ++m) P[m] = acc[m] + red[e * EMB + m];
  }
}

// ---------- kernel 3: partial reduce + bias skip + FC head ----------
__global__ __launch_bounds__(256)
void k_fc(const float* __restrict__ x, const float* __restrict__ emb,
          const float* __restrict__ emb10,
          const float* __restrict__ fc1w, const float* __restrict__ fc1b,
          const float* __restrict__ fc2w, const float* __restrict__ fc2b,
          const float* __restrict__ fc3w, const float* __restrict__ fc3b,
          const float* __restrict__ ws, float* __restrict__ out) {
  int b = blockIdx.x;                   // grid 16
  __shared__ float h0s[E * EMB];
  __shared__ float h1s[FCH];
  __shared__ float h2s[Hd];
  __shared__ float hxs[EMB];
  __shared__ float scratch[256];
  int tid = threadIdx.x;
  {
    int m = tid & 7, g = tid >> 3;      // 32 groups x 8 m
    float p = 0.f;
    for (int l = g; l < Lseq; l += 32)
      p = fmaf(x[b * (Lseq * Nfeat) + l * Nfeat], emb10[l * EMB + m], p);
    scratch[tid] = p;
  }
  __syncthreads();
  if (tid < 8) {
    float s = 0.f;
    for (int g = 0; g < 32; ++g) s += scratch[g * 8 + tid];
    hxs[tid] = s;
  }
  __syncthreads();
  for (int k = tid; k < E * EMB; k += 256) {
    float a = emb[k >> 3] * hxs[k & 7];
    const float* P = ws + OFF_P + b * (E * EMB) + k;
    #pragma unroll 16
    for (int c = 0; c < 128; ++c) a += P[c * (16 * E * EMB)];
    h0s[k] = a;
  }
  __syncthreads();
  {
    int o = tid & 63, kc = tid >> 6;    // 4-way K split
    const float* wrow = fc1w + o * (E * EMB) + kc * 256;
    const float* hh = h0s + kc * 256;
    float a = 0.f;
    #pragma unroll 8
    for (int k = 0; k < 256; ++k) a = fmaf(hh[k], wrow[k], a);
    scratch[tid] = a;
  }
  __syncthreads();
  if (tid < FCH) {
    float a = fc1b[tid] + scratch[tid] + scratch[tid + 64] +
              scratch[tid + 128] + scratch[tid + 192];
    h1s[tid] = a > 0.f ? a : 0.01f * a;
  }
  __syncthreads();
  {
    float a = fc2b[tid];
    const float* wrow = fc2w + tid * FCH;
    #pragma unroll 8
    for (int c = 0; c < FCH; ++c) a = fmaf(h1s[c], wrow[c], a);
    h2s[tid] = a > 0.f ? a : 0.01f * a;
  }
  __syncthreads();
  {
    int o = tid & 127, kc = tid >> 7;   // 2-way K split
    float a = 0.f;
    if (o < PRE) {
      const float* wrow = fc3w + o * Hd + kc * 128;
      const float* hh = h2s + kc * 128;
      #pragma unroll 8
      for (int k = 0; k < 128; ++k) a = fmaf(hh[k], wrow[k], a);
    }
    scratch[tid] = a;
  }
  __syncthreads();
  if (tid < PRE) out[b * PRE + tid] = fc3b[tid] + scratch[tid] + scratch[tid + 128];
}

extern "C" void kernel_launch(void* const* d_in, const int* in_sizes, int n_in,
                              void* d_out, int out_size, void* d_ws, size_t ws_size,
                              hipStream_t stream) {
  const float* x     = (const float*)d_in[0];
  const float* emb   = (const float*)d_in[1];
  const float* w0    = (const float*)d_in[2];
  const float* b0    = (const float*)d_in[3];
  const float* w1    = (const float*)d_in[4];
  const float* b1    = (const float*)d_in[5];
  const float* w2    = (const float*)d_in[6];
  const float* b2    = (const float*)d_in[7];
  const float* emb10 = (const float*)d_in[8];
  const float* fc1w  = (const float*)d_in[9];
  const float* fc1b  = (const float*)d_in[10];
  const float* fc2w  = (const float*)d_in[11];
  const float* fc2b  = (const float*)d_in[12];
  const float* fc3w  = (const float*)d_in[13];
  const float* fc3b  = (const float*)d_in[14];
  float* ws  = (float*)d_ws;
  float* out = (float*)d_out;

  k_prep<<<dim3(2049), 256, 0, stream>>>(x, emb10, ws);
  k_gcf<<<dim3(128, Bsz), 256, 0, stream>>>(emb, w0, b0, w1, b1, w2, b2, ws);
  k_fc<<<dim3(Bsz), 256, 0, stream>>>(x, emb, emb10, fc1w, fc1b, fc2w, fc2b,
                                      fc3w, fc3b, ws, out);
}

// Round 4
// 160.484 us; speedup vs baseline: 1.5545x; 1.1004x over previous
//
#include <hip/hip_runtime.h>
#include <math.h>

// Problem constants
#define Bsz   16
#define Lseq  512
#define Nfeat 32
#define E     128
#define EMB   8
#define FCH   64
#define Hd    256
#define PRE   96
#define M     16384   // N*L
#define MH    8193    // M/2+1
#define LAMBDA 0.01f

// workspace layout (float offsets)
#define OFF_G   0          // four-step intermediate: 16*128*128*2 = 524288 floats
#define OFF_CS  524288     // C/S table: 8193*16 floats
#define OFF_P   655376     // partials: P[f1][b][k] = 128*16*1024 floats
#define OFF_H0  2752528    // reduced h0: 16*1024 floats
// total = 2768912 floats = 11.08 MB

#define TWO_PI_M   3.83495196971410293e-4f   // 2*pi/16384
#define TWO_PI_128 4.90873852123405245e-2f   // 2*pi/128

// ---------- kernel 1: CS tables (blocks 0..256) + FFT pass1 (257..1280) ----------
__global__ __launch_bounds__(256)
void k_prep(const float* __restrict__ x, const float* __restrict__ emb10,
            float* __restrict__ ws) {
  __shared__ float smem[Lseq * EMB];   // 16 KiB (cs); fft1 uses first 256 floats
  int bid = blockIdx.x, tid = threadIdx.x;
  if (bid < 257) {
    // ----- C/S: C[f,m] = wf * sum_t cos(2pi f t/M) emb10[t,m]; 32 f per block
    for (int i = tid; i < Lseq * EMB; i += 256) smem[i] = emb10[i];
    __syncthreads();
    int floc = tid >> 5, tl = tid & 31;
    #pragma unroll
    for (int ff = 0; ff < 4; ++ff) {
      int f = bid * 32 + ff * 8 + floc;
      if (f <= 8192) {
        float ca[EMB], sa[EMB];
        #pragma unroll
        for (int m = 0; m < EMB; ++m) { ca[m] = 0.f; sa[m] = 0.f; }
        #pragma unroll 4
        for (int i = 0; i < 16; ++i) {
          int t = tl + 32 * i;
          int k = (f * t) & (M - 1);
          float ss, cc;
          sincosf((float)k * TWO_PI_M, &ss, &cc);
          const float* er = smem + t * EMB;
          #pragma unroll
          for (int m = 0; m < EMB; ++m) {
            ca[m] = fmaf(cc, er[m], ca[m]);
            sa[m] = fmaf(ss, er[m], sa[m]);
          }
        }
        #pragma unroll
        for (int off = 16; off >= 1; off >>= 1) {
          #pragma unroll
          for (int m = 0; m < EMB; ++m) {
            ca[m] += __shfl_xor(ca[m], off, 64);
            sa[m] += __shfl_xor(sa[m], off, 64);
          }
        }
        if (tl == 0) {
          float wf = (f == 0 || f == 8192) ? (1.0f / 128.0f) : (2.0f / 128.0f);
          float* o = ws + OFF_CS + f * 16;
          #pragma unroll
          for (int m = 0; m < EMB; ++m) { o[m] = ca[m] * wf; o[8 + m] = sa[m] * wf; }
        }
      }
    }
  } else {
    // ----- FFT pass 1: G'[b,f1,t1] = twiddle * sum_t2 x[t1+128 t2] W128^{f1 t2}
    int v = bid - 257;                   // 0..1023
    int b = v >> 6, t1base = (v & 63) << 1;
    int t1loc = tid >> 7, idx = tid & 127;
    {
      int t = (t1base + t1loc) + 128 * idx;
      int n = t >> 9, l = t & 511;
      smem[t1loc * 128 + idx] = x[b * (Lseq * Nfeat) + l * Nfeat + n];
    }
    __syncthreads();
    int f1 = idx, t1 = t1base + t1loc;
    float s1, c1; sincosf((float)f1 * TWO_PI_128, &s1, &c1);
    float c2 = c1 * c1 - s1 * s1, s2 = 2.f * s1 * c1;
    float cA = 1.f, sA = 0.f, cB = c1, sB = s1;
    float grA = 0.f, giA = 0.f, grB = 0.f, giB = 0.f;
    const float* xc = smem + t1loc * 128;
    #pragma unroll 8
    for (int t2 = 0; t2 < 128; t2 += 2) {
      float x0 = xc[t2], x1 = xc[t2 + 1];
      grA = fmaf(x0, cA, grA); giA = fmaf(x0, -sA, giA);
      grB = fmaf(x1, cB, grB); giB = fmaf(x1, -sB, giB);
      float cn = cA * c2 - sA * s2; sA = sA * c2 + cA * s2; cA = cn;
      cn = cB * c2 - sB * s2;       sB = sB * c2 + cB * s2; cB = cn;
    }
    float gr = grA + grB, gi = giA + giB;
    float sb, cb; sincosf((float)(f1 * t1) * TWO_PI_M, &sb, &cb);
    float grr = gr * cb + gi * sb;
    float gii = gi * cb - gr * sb;
    float* G = ws + OFF_G + ((b * 128 + f1) * 128 + t1) * 2;
    G[0] = grr;
    G[1] = gii;
  }
}

// ---------- kernel 2: fused FFT pass2 + fourierGC + partial reduction ----------
__global__ __launch_bounds__(256)
void k_gcf(const float* __restrict__ emb,
           const float* __restrict__ w0, const float* __restrict__ b0,
           const float* __restrict__ w1, const float* __restrict__ b1,
           const float* __restrict__ w2, const float* __restrict__ b2,
           float* __restrict__ ws) {
  int f1 = blockIdx.x, b = blockIdx.y, tid = threadIdx.x;
  int nf2 = (f1 == 0) ? 65 : 64;       // f = f1 + 128*f2 <= 8192
  __shared__ float2 Gs[128];
  __shared__ float Xp[4][65][2];
  __shared__ float CSs[65 * 16];       // reused as red[1024] after phase B
  {
    const float2* gsrc = (const float2*)(ws + OFF_G + (b * 128 + f1) * 256);
    if (tid < 128) Gs[tid] = gsrc[tid];
    for (int j = tid; j < nf2 * 16; j += 256) {
      int i = j >> 4, m = j & 15;
      CSs[j] = ws[OFF_CS + (f1 + 128 * i) * 16 + m];
    }
  }
  __syncthreads();
  // phase A: X[f1+128 f2] = sum_t1 G'[t1] W128^{f2 t1}; t1 split into 4 quarters
  {
    int f2 = tid & 63, q = tid >> 6;
    int r = (f2 * q) & 3;              // start angle = f2*q*(pi/2): exact
    float c = (r == 0) ? 1.f : (r == 2) ? -1.f : 0.f;
    float s = (r == 1) ? 1.f : (r == 3) ? -1.f : 0.f;
    float s1, c1; sincosf((float)f2 * TWO_PI_128, &s1, &c1);
    float xr = 0.f, xi = 0.f;
    int t1 = q * 32;
    #pragma unroll 8
    for (int k = 0; k < 32; ++k) {
      float2 g = Gs[t1 + k];
      xr = fmaf(g.x, c, xr); xr = fmaf(g.y, s, xr);
      xi = fmaf(g.y, c, xi); xi = fmaf(-g.x, s, xi);
      float cn = c * c1 - s * s1; s = s * c1 + c * s1; c = cn;
    }
    Xp[q][f2][0] = xr; Xp[q][f2][1] = xi;
    if (f1 == 0 && f2 == 0) {          // extra f2=64 (f=8192): W = (-1)^t1
      float er = 0.f, ei = 0.f;
      #pragma unroll 8
      for (int k = 0; k < 32; ++k) {
        float2 g = Gs[t1 + k];
        float sg = ((t1 + k) & 1) ? -1.f : 1.f;
        er = fmaf(g.x, sg, er); ei = fmaf(g.y, sg, ei);
      }
      Xp[q][64][0] = er; Xp[q][64][1] = ei;
    }
  }
  __syncthreads();
  // phase B: GC chain + CS-weighted reduction over this block's f-set
  int e = tid & 127, fh = tid >> 7;
  float se  = emb[e] * (1.0f / 128.0f);  // ortho forward scale
  float d00 = w0[e * 129], d01 = w0[E * E + e * 129];
  float c00 = b0[e],       c01 = b0[E + e];
  float d10 = w1[e * 129], d11 = w1[E * E + e * 129];
  float c10 = b1[e],       c11 = b1[E + e];
  float d20 = w2[e * 129], d21 = w2[E * E + e * 129];
  float c20 = b2[e],       c21 = b2[E + e];
  float acc[EMB];
  #pragma unroll
  for (int m = 0; m < EMB; ++m) acc[m] = 0.f;

  for (int i = fh; i < nf2; i += 2) {
    float xr = ((Xp[0][i][0] + Xp[1][i][0]) + (Xp[2][i][0] + Xp[3][i][0])) * se;
    float xi = ((Xp[0][i][1] + Xp[1][i][1]) + (Xp[2][i][1] + Xp[3][i][1])) * se;
    float or0 = fmaxf(fmaf(xr, d00, fmaf(-xi, d01, c00)), 0.f);
    float oi0 = fmaxf(fmaf(xi, d00, fmaf(xr, d01, c01)), 0.f);
    float pr = fmaxf(or0 - LAMBDA, 0.f), pi = fmaxf(oi0 - LAMBDA, 0.f);
    float or1 = fmaxf(fmaf(or0, d10, fmaf(-oi0, d11, c10)), 0.f);
    float oi1 = fmaxf(fmaf(oi0, d10, fmaf(or1, d11, c11)), 0.f);
    pr += fmaxf(or1 - LAMBDA, 0.f); pi += fmaxf(oi1 - LAMBDA, 0.f);
    float or2 = fmaxf(fmaf(or1, d20, fmaf(-oi1, d21, c20)), 0.f);
    float oi2 = fmaxf(fmaf(oi1, d20, fmaf(or2, d21, c21)), 0.f);
    float zr = fmaxf(or2 - LAMBDA, 0.f) + pr;
    float zi = fmaxf(oi2 - LAMBDA, 0.f) + pi;
    const float* cs = &CSs[i * 16];
    #pragma unroll
    for (int m = 0; m < EMB; ++m)
      acc[m] = fmaf(zr, cs[m], fmaf(-zi, cs[8 + m], acc[m]));
  }
  __syncthreads();                      // everyone done reading CSs
  float* red = CSs;
  if (fh == 1) {
    #pragma unroll
    for (int m = 0; m < EMB; ++m) red[e * EMB + m] = acc[m];
  }
  __syncthreads();
  if (fh == 0) {
    float* P = ws + OFF_P + (f1 * 16 + b) * (E * EMB) + e * EMB;
    #pragma unroll
    for (int m = 0; m < EMB; ++m) P[m] = acc[m] + red[e * EMB + m];
  }
}

// ---------- kernel 3: parallel partial reduce: h0[b,k] = sum_f1 P[f1,b,k] ----------
__global__ __launch_bounds__(256)
void k_red(float* __restrict__ ws) {
  int bid = blockIdx.x;                 // 256 = 16 b x 16 kq
  int b = bid >> 4, kq = bid & 15;
  int tid = threadIdx.x;
  int kk = tid & 63, f1g = tid >> 6;
  int k = kq * 64 + kk;
  const float* P = ws + OFF_P + b * (E * EMB) + k;
  float a = 0.f;
  #pragma unroll 8
  for (int j = 0; j < 32; ++j)
    a += P[(f1g * 32 + j) * (16 * E * EMB)];
  __shared__ float sh[256];
  sh[tid] = a;
  __syncthreads();
  if (tid < 64)
    ws[OFF_H0 + b * (E * EMB) + k] = sh[tid] + sh[tid + 64] + sh[tid + 128] + sh[tid + 192];
}

// ---------- kernel 4: bias skip + FC head (wave-per-output, coalesced) ----------
__global__ __launch_bounds__(1024)
void k_fc(const float* __restrict__ x, const float* __restrict__ emb,
          const float* __restrict__ emb10,
          const float* __restrict__ fc1w, const float* __restrict__ fc1b,
          const float* __restrict__ fc2w, const float* __restrict__ fc2b,
          const float* __restrict__ fc3w, const float* __restrict__ fc3b,
          const float* __restrict__ ws, float* __restrict__ out) {
  int b = blockIdx.x;                   // grid 16
  __shared__ float h0s[E * EMB];
  __shared__ float h1s[FCH];
  __shared__ float h2s[Hd];
  __shared__ float hxs[EMB];
  __shared__ float scratch[1024];
  int tid = threadIdx.x;
  int lane = tid & 63, w = tid >> 6;    // 16 waves
  {
    int m = tid & 7, g = tid >> 3;      // 128 groups x 8 m
    float p = 0.f;
    #pragma unroll
    for (int l = g; l < Lseq; l += 128)
      p = fmaf(x[b * (Lseq * Nfeat) + l * Nfeat], emb10[l * EMB + m], p);
    scratch[tid] = p;
  }
  __syncthreads();
  if (tid < 8) {
    float s = 0.f;
    #pragma unroll 16
    for (int g = 0; g < 128; ++g) s += scratch[g * 8 + tid];
    hxs[tid] = s;
  }
  __syncthreads();
  h0s[tid] = ws[OFF_H0 + b * (E * EMB) + tid] + emb[tid >> 3] * hxs[tid & 7];
  __syncthreads();
  // fc1: 64 outputs, K=1024; wave handles one o per oo-iter (coalesced weights)
  #pragma unroll
  for (int oo = 0; oo < 4; ++oo) {
    int o = oo * 16 + w;
    const float* wr = fc1w + o * (E * EMB);
    float a = 0.f;
    #pragma unroll
    for (int j = 0; j < 16; ++j) a = fmaf(h0s[lane + 64 * j], wr[lane + 64 * j], a);
    #pragma unroll
    for (int off = 32; off >= 1; off >>= 1) a += __shfl_xor(a, off, 64);
    if (lane == 0) { float v = a + fc1b[o]; h1s[o] = v > 0.f ? v : 0.01f * v; }
  }
  __syncthreads();
  // fc2: 256 outputs, K=64
  #pragma unroll
  for (int oo = 0; oo < 16; ++oo) {
    int o = oo * 16 + w;
    float a = h1s[lane] * fc2w[o * FCH + lane];
    #pragma unroll
    for (int off = 32; off >= 1; off >>= 1) a += __shfl_xor(a, off, 64);
    if (lane == 0) { float v = a + fc2b[o]; h2s[o] = v > 0.f ? v : 0.01f * v; }
  }
  __syncthreads();
  // fc3: 96 outputs, K=256
  #pragma unroll
  for (int oo = 0; oo < 6; ++oo) {
    int o = oo * 16 + w;
    const float* wr = fc3w + o * Hd;
    float a = 0.f;
    #pragma unroll
    for (int j = 0; j < 4; ++j) a = fmaf(h2s[lane + 64 * j], wr[lane + 64 * j], a);
    #pragma unroll
    for (int off = 32; off >= 1; off >>= 1) a += __shfl_xor(a, off, 64);
    if (lane == 0) out[b * PRE + o] = a + fc3b[o];
  }
}

extern "C" void kernel_launch(void* const* d_in, const int* in_sizes, int n_in,
                              void* d_out, int out_size, void* d_ws, size_t ws_size,
                              hipStream_t stream) {
  const float* x     = (const float*)d_in[0];
  const float* emb   = (const float*)d_in[1];
  const float* w0    = (const float*)d_in[2];
  const float* b0    = (const float*)d_in[3];
  const float* w1    = (const float*)d_in[4];
  const float* b1    = (const float*)d_in[5];
  const float* w2    = (const float*)d_in[6];
  const float* b2    = (const float*)d_in[7];
  const float* emb10 = (const float*)d_in[8];
  const float* fc1w  = (const float*)d_in[9];
  const float* fc1b  = (const float*)d_in[10];
  const float* fc2w  = (const float*)d_in[11];
  const float* fc2b  = (const float*)d_in[12];
  const float* fc3w  = (const float*)d_in[13];
  const float* fc3b  = (const float*)d_in[14];
  float* ws  = (float*)d_ws;
  float* out = (float*)d_out;

  k_prep<<<dim3(1281), 256, 0, stream>>>(x, emb10, ws);
  k_gcf<<<dim3(128, Bsz), 256, 0, stream>>>(emb, w0, b0, w1, b1, w2, b2, ws);
  k_red<<<dim3(256), 256, 0, stream>>>(ws);
  k_fc<<<dim3(Bsz), 1024, 0, stream>>>(x, emb, emb10, fc1w, fc1b, fc2w, fc2b,
                                       fc3w, fc3b, ws, out);
}

// Round 5
// 153.402 us; speedup vs baseline: 1.6263x; 1.0462x over previous
//
#include <hip/hip_runtime.h>
#include <math.h>

// Problem constants
#define Bsz   16
#define Lseq  512
#define Nfeat 32
#define E     128
#define EMB   8
#define FCH   64
#define Hd    256
#define PRE   96
#define M     16384   // N*L
#define MH    8193    // M/2+1
#define LAMBDA 0.01f

// workspace layout (float offsets)
#define OFF_G   0          // four-step intermediate: 16*128*128*2 = 524288 floats
#define OFF_CS  524288     // C/S table: 8193*16 floats (padded to 131088)
#define OFF_P   655376     // partials: P[f1][b][k] = 128*16*1024 floats
// total = 2752528 floats = 11.01 MB

#define TWO_PI_M   3.83495196971410293e-4f   // 2*pi/16384
#define TWO_PI_128 4.90873852123405245e-2f   // 2*pi/128

// ---------- kernel 1: CS tables (blocks 0..256) + FFT pass1 (257..1280) ----------
__global__ __launch_bounds__(256)
void k_prep(const float* __restrict__ x, const float* __restrict__ emb10,
            float* __restrict__ ws) {
  __shared__ float smem[Lseq * EMB];   // 16 KiB (cs); fft1 uses first 256 floats
  int bid = blockIdx.x, tid = threadIdx.x;
  if (bid < 257) {
    // ----- C/S: C[f,m] = wf * sum_t cos(2pi f t/M) emb10[t,m]; 32 f per block
    for (int i = tid; i < Lseq * EMB; i += 256) smem[i] = emb10[i];
    __syncthreads();
    int floc = tid >> 5, tl = tid & 31;
    #pragma unroll
    for (int ff = 0; ff < 4; ++ff) {
      int f = bid * 32 + ff * 8 + floc;
      if (f <= 8192) {
        float ca[EMB], sa[EMB];
        #pragma unroll
        for (int m = 0; m < EMB; ++m) { ca[m] = 0.f; sa[m] = 0.f; }
        #pragma unroll 4
        for (int i = 0; i < 16; ++i) {
          int t = tl + 32 * i;
          int k = (f * t) & (M - 1);
          float ss, cc;
          sincosf((float)k * TWO_PI_M, &ss, &cc);
          const float* er = smem + t * EMB;
          #pragma unroll
          for (int m = 0; m < EMB; ++m) {
            ca[m] = fmaf(cc, er[m], ca[m]);
            sa[m] = fmaf(ss, er[m], sa[m]);
          }
        }
        #pragma unroll
        for (int off = 16; off >= 1; off >>= 1) {
          #pragma unroll
          for (int m = 0; m < EMB; ++m) {
            ca[m] += __shfl_xor(ca[m], off, 64);
            sa[m] += __shfl_xor(sa[m], off, 64);
          }
        }
        if (tl == 0) {
          float wf = (f == 0 || f == 8192) ? (1.0f / 128.0f) : (2.0f / 128.0f);
          float* o = ws + OFF_CS + f * 16;
          #pragma unroll
          for (int m = 0; m < EMB; ++m) { o[m] = ca[m] * wf; o[8 + m] = sa[m] * wf; }
        }
      }
    }
  } else {
    // ----- FFT pass 1: G'[b,f1,t1] = twiddle * sum_t2 x[t1+128 t2] W128^{f1 t2}
    int v = bid - 257;                   // 0..1023
    int b = v >> 6, t1base = (v & 63) << 1;
    int t1loc = tid >> 7, idx = tid & 127;
    {
      int t = (t1base + t1loc) + 128 * idx;
      int n = t >> 9, l = t & 511;
      smem[t1loc * 128 + idx] = x[b * (Lseq * Nfeat) + l * Nfeat + n];
    }
    __syncthreads();
    int f1 = idx, t1 = t1base + t1loc;
    float s1, c1; sincosf((float)f1 * TWO_PI_128, &s1, &c1);
    float c2 = c1 * c1 - s1 * s1, s2 = 2.f * s1 * c1;
    float cA = 1.f, sA = 0.f, cB = c1, sB = s1;
    float grA = 0.f, giA = 0.f, grB = 0.f, giB = 0.f;
    const float* xc = smem + t1loc * 128;
    #pragma unroll 8
    for (int t2 = 0; t2 < 128; t2 += 2) {
      float x0 = xc[t2], x1 = xc[t2 + 1];
      grA = fmaf(x0, cA, grA); giA = fmaf(x0, -sA, giA);
      grB = fmaf(x1, cB, grB); giB = fmaf(x1, -sB, giB);
      float cn = cA * c2 - sA * s2; sA = sA * c2 + cA * s2; cA = cn;
      cn = cB * c2 - sB * s2;       sB = sB * c2 + cB * s2; cB = cn;
    }
    float gr = grA + grB, gi = giA + giB;
    float sb, cb; sincosf((float)(f1 * t1) * TWO_PI_M, &sb, &cb);
    float grr = gr * cb + gi * sb;
    float gii = gi * cb - gr * sb;
    float* G = ws + OFF_G + ((b * 128 + f1) * 128 + t1) * 2;
    G[0] = grr;
    G[1] = gii;
  }
}

// ---------- kernel 2: fused FFT pass2 + fourierGC + partial reduction ----------
__global__ __launch_bounds__(256)
void k_gcf(const float* __restrict__ emb,
           const float* __restrict__ w0, const float* __restrict__ b0,
           const float* __restrict__ w1, const float* __restrict__ b1,
           const float* __restrict__ w2, const float* __restrict__ b2,
           float* __restrict__ ws) {
  int f1 = blockIdx.x, b = blockIdx.y, tid = threadIdx.x;
  int nf2 = (f1 == 0) ? 65 : 64;       // f = f1 + 128*f2 <= 8192
  __shared__ float2 Gs[132];           // stride-33 padded quarters (bank-safe)
  __shared__ float2 Xs[65];
  __shared__ float red[E * EMB];
  if (tid < 128)
    Gs[(tid >> 5) * 33 + (tid & 31)] =
        ((const float2*)(ws + OFF_G + (b * 128 + f1) * 256))[tid];
  __syncthreads();
  // phase A: X[f1+128 f2] = sum_t1 G'[t1] W128^{f2 t1}
  // lane = q*16 + f2l; quarter partials reduced in-wave via shfl
  {
    int lane = tid & 63, w = tid >> 6;
    int q = lane >> 4, f2l = lane & 15;
    int f2 = w * 16 + f2l;
    int r = (f2 * q) & 3;              // start angle = f2*q*(pi/2): exact
    float c = (r == 0) ? 1.f : (r == 2) ? -1.f : 0.f;
    float s = (r == 1) ? 1.f : (r == 3) ? -1.f : 0.f;
    float s1, c1; sincosf((float)f2 * TWO_PI_128, &s1, &c1);
    float xr = 0.f, xi = 0.f;
    const float2* g = Gs + q * 33;
    #pragma unroll 8
    for (int k = 0; k < 32; ++k) {
      float2 gv = g[k];
      xr = fmaf(gv.x, c, xr); xr = fmaf(gv.y, s, xr);
      xi = fmaf(gv.y, c, xi); xi = fmaf(-gv.x, s, xi);
      float cn = c * c1 - s * s1; s = s * c1 + c * s1; c = cn;
    }
    xr += __shfl_xor(xr, 16, 64); xi += __shfl_xor(xi, 16, 64);
    xr += __shfl_xor(xr, 32, 64); xi += __shfl_xor(xi, 32, 64);
    if (lane < 16) Xs[f2] = make_float2(xr, xi);
    if (f1 == 0 && tid < 32) {         // f2=64 (f=8192): W = (-1)^t1
      float er = 0.f, ei = 0.f;
      #pragma unroll
      for (int j = 0; j < 4; ++j) {
        int t1v = tid * 4 + j;
        float2 gv = Gs[(t1v >> 5) * 33 + (t1v & 31)];
        float sg = (j & 1) ? -1.f : 1.f;
        er = fmaf(gv.x, sg, er); ei = fmaf(gv.y, sg, ei);
      }
      #pragma unroll
      for (int off = 1; off <= 16; off <<= 1) {
        er += __shfl_xor(er, off, 64);
        ei += __shfl_xor(ei, off, 64);
      }
      if (tid == 0) Xs[64] = make_float2(er, ei);
    }
  }
  __syncthreads();
  // phase B: GC chain + CS-weighted reduction; CS via scalar loads (SMEM)
  int e = tid & 127, fh = tid >> 7;
  float se  = emb[e] * (1.0f / 128.0f);  // ortho forward scale
  float d00 = w0[e * 129], d01 = w0[E * E + e * 129];
  float c00 = b0[e],       c01 = b0[E + e];
  float d10 = w1[e * 129], d11 = w1[E * E + e * 129];
  float c10 = b1[e],       c11 = b1[E + e];
  float d20 = w2[e * 129], d21 = w2[E * E + e * 129];
  float c20 = b2[e],       c21 = b2[E + e];
  float acc[EMB];
  #pragma unroll
  for (int m = 0; m < EMB; ++m) acc[m] = 0.f;
  const float* csbase = ws + OFF_CS + f1 * 16;

  for (int i = fh; i < nf2; i += 2) {
    int iu = __builtin_amdgcn_readfirstlane(i);      // wave-uniform -> s_load
    const float* cs = csbase + (iu << 11);           // (f1 + 128*i)*16
    float2 X = Xs[i];
    float xr = X.x * se, xi = X.y * se;
    float or0 = fmaxf(fmaf(xr, d00, fmaf(-xi, d01, c00)), 0.f);
    float oi0 = fmaxf(fmaf(xi, d00, fmaf(xr, d01, c01)), 0.f);
    float pr = fmaxf(or0 - LAMBDA, 0.f), pi = fmaxf(oi0 - LAMBDA, 0.f);
    float or1 = fmaxf(fmaf(or0, d10, fmaf(-oi0, d11, c10)), 0.f);
    float oi1 = fmaxf(fmaf(oi0, d10, fmaf(or1, d11, c11)), 0.f);
    pr += fmaxf(or1 - LAMBDA, 0.f); pi += fmaxf(oi1 - LAMBDA, 0.f);
    float u2r = fmaf(or1, d20, fmaf(-oi1, d21, c20));
    float or2 = fmaxf(u2r, 0.f);
    float u2i = fmaf(oi1, d20, fmaf(or2, d21, c21));
    float zr = fmaxf(u2r - LAMBDA, 0.f) + pr;        // shrink(relu(u)) = max(u-l,0)
    float zi = fmaxf(u2i - LAMBDA, 0.f) + pi;
    #pragma unroll
    for (int m = 0; m < EMB; ++m)
      acc[m] = fmaf(zr, cs[m], fmaf(-zi, cs[8 + m], acc[m]));
  }
  __syncthreads();
  if (fh == 1) {
    #pragma unroll
    for (int m = 0; m < EMB; ++m) red[e * EMB + m] = acc[m];
  }
  __syncthreads();
  if (fh == 0) {
    float* P = ws + OFF_P + (f1 * 16 + b) * (E * EMB) + e * EMB;
    #pragma unroll
    for (int m = 0; m < EMB; ++m) P[m] = acc[m] + red[e * EMB + m];
  }
}

// ---------- kernel 3: P-reduce + bias skip + FC head ----------
__global__ __launch_bounds__(1024)
void k_fc(const float* __restrict__ x, const float* __restrict__ emb,
          const float* __restrict__ emb10,
          const float* __restrict__ fc1w, const float* __restrict__ fc1b,
          const float* __restrict__ fc2w, const float* __restrict__ fc2b,
          const float* __restrict__ fc3w, const float* __restrict__ fc3b,
          const float* __restrict__ ws, float* __restrict__ out) {
  int b = blockIdx.x;                   // grid 16
  __shared__ float h0s[E * EMB];
  __shared__ float h1s[FCH];
  __shared__ float h2s[Hd];             // also hx wave-partial scratch
  __shared__ float hxs[EMB];
  int tid = threadIdx.x;
  int lane = tid & 63, w = tid >> 6;    // 16 waves
  // hx[m] = sum_l x[b,l,0] * emb10[l,m]  (in-wave shuffle reduce)
  {
    int m = lane & 7, g8 = lane >> 3;
    int gg = w * 8 + g8;                // 128 l-groups
    float p = 0.f;
    #pragma unroll
    for (int l = gg; l < Lseq; l += 128)
      p = fmaf(x[b * (Lseq * Nfeat) + l * Nfeat], emb10[l * EMB + m], p);
    p += __shfl_xor(p, 8, 64);
    p += __shfl_xor(p, 16, 64);
    p += __shfl_xor(p, 32, 64);
    if (lane < 8) h2s[w * 8 + lane] = p;
  }
  // P-reduce (independent loads, overlaps hx)
  const float* P = ws + OFF_P + b * (E * EMB) + tid;
  float a = 0.f;
  #pragma unroll 16
  for (int j = 0; j < 128; ++j) a += P[j * (16 * E * EMB)];
  __syncthreads();
  if (tid < 8) {
    float s = 0.f;
    #pragma unroll
    for (int wv = 0; wv < 16; ++wv) s += h2s[wv * 8 + tid];
    hxs[tid] = s;
  }
  __syncthreads();
  h0s[tid] = a + emb[tid >> 3] * hxs[tid & 7];
  __syncthreads();
  // fc1: 64 outputs, K=1024; wave-per-output, coalesced weights
  #pragma unroll
  for (int oo = 0; oo < 4; ++oo) {
    int o = oo * 16 + w;
    const float* wr = fc1w + o * (E * EMB);
    float acc = 0.f;
    #pragma unroll
    for (int j = 0; j < 16; ++j) acc = fmaf(h0s[lane + 64 * j], wr[lane + 64 * j], acc);
    #pragma unroll
    for (int off = 32; off >= 1; off >>= 1) acc += __shfl_xor(acc, off, 64);
    if (lane == 0) { float v = acc + fc1b[o]; h1s[o] = v > 0.f ? v : 0.01f * v; }
  }
  __syncthreads();
  // fc2: 256 outputs, K=64
  #pragma unroll
  for (int oo = 0; oo < 16; ++oo) {
    int o = oo * 16 + w;
    float acc = h1s[lane] * fc2w[o * FCH + lane];
    #pragma unroll
    for (int off = 32; off >= 1; off >>= 1) acc += __shfl_xor(acc, off, 64);
    if (lane == 0) { float v = acc + fc2b[o]; h2s[o] = v > 0.f ? v : 0.01f * v; }
  }
  __syncthreads();
  // fc3: 96 outputs, K=256
  #pragma unroll
  for (int oo = 0; oo < 6; ++oo) {
    int o = oo * 16 + w;
    const float* wr = fc3w + o * Hd;
    float acc = 0.f;
    #pragma unroll
    for (int j = 0; j < 4; ++j) acc = fmaf(h2s[lane + 64 * j], wr[lane + 64 * j], acc);
    #pragma unroll
    for (int off = 32; off >= 1; off >>= 1) acc += __shfl_xor(acc, off, 64);
    if (lane == 0) out[b * PRE + o] = acc + fc3b[o];
  }
}

extern "C" void kernel_launch(void* const* d_in, const int* in_sizes, int n_in,
                              void* d_out, int out_size, void* d_ws, size_t ws_size,
                              hipStream_t stream) {
  const float* x     = (const float*)d_in[0];
  const float* emb   = (const float*)d_in[1];
  const float* w0    = (const float*)d_in[2];
  const float* b0    = (const float*)d_in[3];
  const float* w1    = (const float*)d_in[4];
  const float* b1    = (const float*)d_in[5];
  const float* w2    = (const float*)d_in[6];
  const float* b2    = (const float*)d_in[7];
  const float* emb10 = (const float*)d_in[8];
  const float* fc1w  = (const float*)d_in[9];
  const float* fc1b  = (const float*)d_in[10];
  const float* fc2w  = (const float*)d_in[11];
  const float* fc2b  = (const float*)d_in[12];
  const float* fc3w  = (const float*)d_in[13];
  const float* fc3b  = (const float*)d_in[14];
  float* ws  = (float*)d_ws;
  float* out = (float*)d_out;

  k_prep<<<dim3(1281), 256, 0, stream>>>(x, emb10, ws);
  k_gcf<<<dim3(128, Bsz), 256, 0, stream>>>(emb, w0, b0, w1, b1, w2, b2, ws);
  k_fc<<<dim3(Bsz), 1024, 0, stream>>>(x, emb, emb10, fc1w, fc1b, fc2w, fc2b,
                                       fc3w, fc3b, ws, out);
}